// Round 14
// baseline (566.576 us; speedup 1.0000x reference)
//
#include <hip/hip_runtime.h>
#include <math.h>
#include <stddef.h>

#define NLAYER 24
#define NEMBD  1024
#define NFFN   4096
#define NB     256
#define NT     256
#define LN_EPS 1e-5f

#define OUT_SA (NEMBD)
#define OUT_SB (NEMBD + NLAYER*NEMBD)
#define OUT_SC (NEMBD + 2*NLAYER*NEMBD)
#define OUT_SD (NEMBD + 3*NLAYER*NEMBD)

typedef unsigned long long u64;
typedef unsigned u32;

// tagged-word queues (u64: tag<<32 | float bits), data IS the sync signal
#define QX_OFF    0        // 1024: x' per layer
#define QW_OFF    1024     // 1024: w vector (producer-side wkv)
#define QSXX_OFF  2048     // 1024: sxx
#define QKFB_OFF  3072     // 4096: kf
#define QTOTAL    7168

// LDS float offsets
#define LMSK  0            // 3072: ln masks / staged w vector
#define LACT  3072         // 4096: staged kf
#define LFF   7168         // 4 x 5120: per-wave FFN weight slabs (80 KB)
#define LLN   27648        // 8: LN partials
#define LXL   27656        // 4: x[b*4+r]   (s1 -> s2)
#define LSXL  27660        // 4: sxx[b*4+r] (s2 -> s4)
#define LRFL  27664        // 4: rf[b*4+r]  (s3 -> s4)
#define LPT   27668        // 16: s4 K-split partials [r*4+wave]
#define SMTOT 27684        // 110736 B

struct Params {
  const float *x, *state, *ln1w, *ln1b, *ln2w, *ln2b, *td, *tf, *kktk, *vvtv, *rrtr;
  const float *key, *outputv, *tmk, *tmr, *kffn, *rffn, *vffn;
  float *out;
  u64 *q;
};

__device__ __forceinline__ float wred(float v) {
#pragma unroll
  for (int o = 32; o > 0; o >>= 1) v += __shfl_xor(v, o, 64);
  return v;
}
__device__ __forceinline__ float dot4(float4 a, float4 b) {
  return a.x*b.x + a.y*b.y + a.z*b.z + a.w*b.w;
}
__device__ __forceinline__ float fcomp(float4 v, int j) {   // literal j only
  return j == 0 ? v.x : (j == 1 ? v.y : (j == 2 ? v.z : v.w));
}
__device__ __forceinline__ u64 qload(const u64* a) {
  return __hip_atomic_load(a, __ATOMIC_RELAXED, __HIP_MEMORY_SCOPE_AGENT);
}
__device__ __forceinline__ void qput(u64* a, float v, u32 tag) {
  u64 w = ((u64)tag << 32) | (u64)__float_as_uint(v);
  __hip_atomic_store(a, w, __ATOMIC_RELAXED, __HIP_MEMORY_SCOPE_AGENT);
}
__device__ __forceinline__ u32   qtag(u64 w) { return (u32)(w >> 32); }
__device__ __forceinline__ float qval(u64 w) { return __uint_as_float((u32)w); }

// async global->LDS, 16B/lane: dest = wave-uniform base + lane*16
__device__ __forceinline__ void stage16(const float* g, float* l) {
  __builtin_amdgcn_global_load_lds(
      (const __attribute__((address_space(1))) unsigned int*)g,
      (__attribute__((address_space(3))) unsigned int*)l, 16, 0, 0);
}

// intra-block barrier: LDS ordering only; weight vmem stays in flight
__device__ __forceinline__ void lbar() {
  asm volatile("s_waitcnt lgkmcnt(0)" ::: "memory");
  __builtin_amdgcn_s_barrier();
  asm volatile("" ::: "memory");
}

// per-thread poll of its own 4 consecutive words
#define POLL4(QB, IDX, TG, OUTA)                                              \
  do {                                                                        \
    u64 a0_, a1_, a2_, a3_; long cc_ = 0;                                     \
    for (;;) {                                                                \
      a0_ = qload((QB) + (IDX) + 0); a1_ = qload((QB) + (IDX) + 1);           \
      a2_ = qload((QB) + (IDX) + 2); a3_ = qload((QB) + (IDX) + 3);           \
      if (qtag(a0_) >= (TG) && qtag(a1_) >= (TG) &&                           \
          qtag(a2_) >= (TG) && qtag(a3_) >= (TG)) break;                      \
      __builtin_amdgcn_s_sleep(1);                                            \
      if (++cc_ > (1L << 20)) break;  /* safety: wrong beats hang */          \
    }                                                                         \
    OUTA[0] = qval(a0_); OUTA[1] = qval(a1_);                                 \
    OUTA[2] = qval(a2_); OUTA[3] = qval(a3_);                                 \
  } while (0)

__global__ void __launch_bounds__(NT, 1)
rwkv_persistent(Params p) {
  const int b    = blockIdx.x;
  const int t    = threadIdx.x;
  const int wid  = t >> 6;
  const int lane = t & 63;
  const int i0   = t * 4;
  const int myi  = b * 4 + wid;     // this wave's owned vector index

  __shared__ float sm[SMTOT];

  u64* QX   = p.q + QX_OFF;
  u64* QW   = p.q + QW_OFF;
  u64* QSXX = p.q + QSXX_OFF;
  u64* QKFB = p.q + QKFB_OFF;

  float4 wKEY[12];   // s1: k,v,r rows for index myi
  float4 wOV[4];     // s2: outputv row myi
  float4 wVF[16];    // s4: vffn 4 rows x this wave's 4 K-chunks
  float4 pA[6];      // s1 params
  float4 pC[5];      // s3 params
  float s_tf, s_sb, s_sc, s_td;   // lane0 wkv scalars for index myi

  auto loadKEY = [&](int L) {
#pragma unroll
    for (int mth = 0; mth < 3; ++mth) {
      const float* W = p.key + ((size_t)L * 3 + mth) * NEMBD * NEMBD
                     + (size_t)myi * NEMBD + lane * 4;
#pragma unroll
      for (int c = 0; c < 4; ++c)
        wKEY[mth * 4 + c] = *(const float4*)&W[c * 256];
    }
  };
  auto loadOV = [&](int L) {
    const float* W = p.outputv + ((size_t)L * NEMBD + myi) * NEMBD + lane * 4;
#pragma unroll
    for (int c = 0; c < 4; ++c)
      wOV[c] = *(const float4*)&W[c * 256];
  };
  auto loadVF = [&](int L) {
#pragma unroll
    for (int r = 0; r < 4; ++r) {
      const float* W = p.vffn + ((size_t)L * NEMBD + b * 4 + r) * NFFN + lane * 4;
#pragma unroll
      for (int c = 0; c < 4; ++c)
        wVF[r * 4 + c] = *(const float4*)&W[(wid * 4 + c) * 256];
    }
  };
  auto stageFF = [&](int L) {       // 4 kffn rows + 1 rffn row -> own LDS slab
    float* slab = &sm[LFF + wid * 5120];
#pragma unroll
    for (int q = 0; q < 4; ++q) {
      const float* W = p.kffn + ((size_t)L * NFFN + b * 16 + wid * 4 + q) * NEMBD;
#pragma unroll
      for (int c = 0; c < 4; ++c)
        stage16(W + c * 256 + lane * 4, slab + q * 1024 + c * 256);
    }
    const float* Wr = p.rffn + ((size_t)L * NEMBD + myi) * NEMBD;
#pragma unroll
    for (int c = 0; c < 4; ++c)
      stage16(Wr + c * 256 + lane * 4, slab + 4096 + c * 256);
  };
  auto loadPA = [&](int L) {
    const int o = L * NEMBD + i0;
    pA[0] = *(const float4*)&p.ln1w[o];
    pA[1] = *(const float4*)&p.ln1b[o];
    pA[2] = *(const float4*)&p.state[0 * NLAYER * NEMBD + o];
    pA[3] = *(const float4*)&p.kktk[o];
    pA[4] = *(const float4*)&p.vvtv[o];
    pA[5] = *(const float4*)&p.rrtr[o];
    if (lane == 0) {
      const int ix = L * NEMBD + myi;
      s_tf = p.tf[ix];
      s_sb = p.state[1 * NLAYER * NEMBD + ix];
      s_sc = p.state[2 * NLAYER * NEMBD + ix];
      s_td = p.td[ix];
    }
  };
  auto loadPC = [&](int L) {
    const int o = L * NEMBD + i0;
    pC[0] = *(const float4*)&p.ln2w[o];
    pC[1] = *(const float4*)&p.ln2b[o];
    pC[2] = *(const float4*)&p.state[3 * NLAYER * NEMBD + o];
    pC[3] = *(const float4*)&p.tmk[o];
    pC[4] = *(const float4*)&p.tmr[o];
  };

  // prologue: layer-0 s1/s2 bundles + params in flight
  loadPA(0); loadKEY(0); loadOV(0);

  for (int l = 0; l < NLAYER; ++l) {
    const u32 t1 = (u32)(4 * l + 1), t2 = t1 + 1, t3 = t1 + 2, t4 = t1 + 3;

    // ===== STAGE 1: x -> [issue FF,VF,pC] -> ln1 -> masks -> k/v/r -> wkv ==
    {
      float xa[4];
      if (l == 0) {
        float4 x4 = *(const float4*)&p.x[i0];
        xa[0] = x4.x; xa[1] = x4.y; xa[2] = x4.z; xa[3] = x4.w;
      } else {
        POLL4(QX, i0, (u32)(4 * l), xa);
      }
      // post-poll issue: these stream through the WHOLE stage (+ next poll)
      stageFF(l); loadVF(l); loadPC(l);
      __builtin_amdgcn_sched_barrier(0);

      if (t == b) {                       // own x slice local for stage 2
#pragma unroll
        for (int j = 0; j < 4; ++j) sm[LXL + j] = xa[j];
      }
      float s = xa[0] + xa[1] + xa[2] + xa[3];
      float q = xa[0]*xa[0] + xa[1]*xa[1] + xa[2]*xa[2] + xa[3]*xa[3];
      s = wred(s); q = wred(q);
      if (lane == 0) { sm[LLN + wid] = s; sm[LLN + 4 + wid] = q; }
      lbar();
      float m  = (sm[LLN+0] + sm[LLN+1] + sm[LLN+2] + sm[LLN+3]) * (1.f / NEMBD);
      float tq = (sm[LLN+4] + sm[LLN+5] + sm[LLN+6] + sm[LLN+7]) * (1.f / NEMBD);
      float rs = rsqrtf(tq - m * m + LN_EPS);
#pragma unroll
      for (int j = 0; j < 4; ++j) {
        int i = i0 + j;
        float xy  = (xa[j] - m) * rs * fcomp(pA[0], j) + fcomp(pA[1], j);
        float sav = fcomp(pA[2], j);
        sm[LMSK + i]        = xy + fcomp(pA[3], j) * sav;
        sm[LMSK + 1024 + i] = xy + fcomp(pA[4], j) * sav;
        sm[LMSK + 2048 + i] = xy + fcomp(pA[5], j) * sav;
        if (t == b) p.out[OUT_SA + l * NEMBD + i] = xy;   // statea: own slice
      }
      lbar();                                             // masks ready
      float a0 = 0.f, a1 = 0.f, a2 = 0.f;
#pragma unroll
      for (int c = 0; c < 4; ++c) {
        int col = lane * 4 + c * 256;
        a0 += dot4(wKEY[c],     *(const float4*)&sm[LMSK + col]);
        a1 += dot4(wKEY[4 + c], *(const float4*)&sm[LMSK + 1024 + col]);
        a2 += dot4(wKEY[8 + c], *(const float4*)&sm[LMSK + 2048 + col]);
      }
      a0 = wred(a0); a1 = wred(a1); a2 = wred(a2);
      if (lane == 0) {                    // producer-side wkv combine
        float etfk = expf(s_tf + a0);
        float er   = expf(a2);
        // sc*er + exp(tf+k+r) + sc + etfk == (sc+etfk)*(1+er)
        float wv = (s_sb + etfk * a1) / ((s_sc + etfk) * (1.f + er));
        qput(&QW[myi], wv, t1);
        float ek = expf(a0), ed = expf(s_td);
        p.out[OUT_SB + l * NEMBD + myi] = s_sb * ed + ek * a1;   // distributed
        p.out[OUT_SC + l * NEMBD + myi] = s_sc * ed + ek;
      }
      lbar();                             // stage end (LMSK reuse barrier)
    }

    // ===== STAGE 2: w -> [issue KEY',pA'] -> outputv dot -> sxx =====
    {
      float wv[4];
      POLL4(QW, i0, t1, wv);
      // this poll's drain retired FF gl2lds (older, in-order) -> S3 slab safe
      if (l + 1 < NLAYER) { loadKEY(l + 1); loadPA(l + 1); }
      __builtin_amdgcn_sched_barrier(0);
#pragma unroll
      for (int j = 0; j < 4; ++j) sm[LMSK + i0 + j] = wv[j];
      lbar();                             // w vector staged
      float acc = 0.f;
#pragma unroll
      for (int c = 0; c < 4; ++c)
        acc += dot4(wOV[c], *(const float4*)&sm[LMSK + lane * 4 + c * 256]);
      acc = wred(acc);
      if (lane == 0) {
        float sxx = sm[LXL + wid] + acc;
        qput(&QSXX[myi], sxx, t2);
        sm[LSXL + wid] = sxx;             // local for stage 4
      }
      lbar();                             // stage end
    }

    // ===== STAGE 3: sxx -> [issue OV'] -> ln2 -> masks -> ffn dots =====
    {
      float xa[4];
      POLL4(QSXX, i0, t2, xa);
      if (l + 1 < NLAYER) loadOV(l + 1);
      __builtin_amdgcn_sched_barrier(0);
      float s = xa[0] + xa[1] + xa[2] + xa[3];
      float q = xa[0]*xa[0] + xa[1]*xa[1] + xa[2]*xa[2] + xa[3]*xa[3];
      s = wred(s); q = wred(q);
      if (lane == 0) { sm[LLN + wid] = s; sm[LLN + 4 + wid] = q; }
      lbar();
      float m  = (sm[LLN+0] + sm[LLN+1] + sm[LLN+2] + sm[LLN+3]) * (1.f / NEMBD);
      float tq = (sm[LLN+4] + sm[LLN+5] + sm[LLN+6] + sm[LLN+7]) * (1.f / NEMBD);
      float rs = rsqrtf(tq - m * m + LN_EPS);
#pragma unroll
      for (int j = 0; j < 4; ++j) {
        int i = i0 + j;
        float xx  = (xa[j] - m) * rs * fcomp(pC[0], j) + fcomp(pC[1], j);
        float sdv = fcomp(pC[2], j);
        sm[LMSK + i]        = xx + fcomp(pC[3], j) * sdv;
        sm[LMSK + 1024 + i] = xx + fcomp(pC[4], j) * sdv;
        if (t == b) p.out[OUT_SD + l * NEMBD + i] = xx;   // stated: own slice
      }
      lbar();                             // masks ready; FF slab landed
      const float* slab = &sm[LFF + wid * 5120];
#pragma unroll
      for (int q2 = 0; q2 < 4; ++q2) {
        float a = 0.f;
#pragma unroll
        for (int c = 0; c < 4; ++c) {
          int col = lane * 4 + c * 256;
          a += dot4(*(const float4*)&slab[q2 * 1024 + col],
                    *(const float4*)&sm[LMSK + col]);
        }
        a = wred(a);
        if (lane == 0) {
          float kv = fmaxf(a, 0.f);
          qput(&QKFB[b * 16 + wid * 4 + q2], kv * kv, t3);
        }
      }
      {
        float a = 0.f;
#pragma unroll
        for (int c = 0; c < 4; ++c) {
          int col = lane * 4 + c * 256;
          a += dot4(*(const float4*)&slab[4096 + col],
                    *(const float4*)&sm[LMSK + 1024 + col]);
        }
        a = wred(a);
        if (lane == 0) sm[LRFL + wid] = expf(a);   // block-local only
      }
      lbar();                             // stage end
    }

    // ===== STAGE 4: kf -> vffn dot (K-split) -> x' =====
    {
#pragma unroll
      for (int c = 0; c < 4; ++c) {
        float ka[4];
        POLL4(QKFB, c * 1024 + i0, t3, ka);
#pragma unroll
        for (int j = 0; j < 4; ++j) sm[LACT + c * 1024 + i0 + j] = ka[j];
      }
      lbar();                             // kf staged
#pragma unroll
      for (int r = 0; r < 4; ++r) {
        float a = 0.f;
#pragma unroll
        for (int c = 0; c < 4; ++c)
          a += dot4(wVF[r * 4 + c],
                    *(const float4*)&sm[LACT + lane * 4 + (wid * 4 + c) * 256]);
        a = wred(a);
        if (lane == 0) sm[LPT + r * 4 + wid] = a;
      }
      lbar();                             // partials ready
      if (t < 4) {
        float tot = sm[LPT + t * 4 + 0] + sm[LPT + t * 4 + 1]
                  + sm[LPT + t * 4 + 2] + sm[LPT + t * 4 + 3];
        float xn = sm[LSXL + t] + tot / (sm[LRFL + t] + 1.f);
        if (l == NLAYER - 1) p.out[b * 4 + t] = xn;   // final x_out
        else                 qput(&QX[b * 4 + t], xn, t4);
      }
    }
  }
}

__global__ void rwkv_init(u64* q) {
  for (int i = 0; i < 28; ++i)
    q[threadIdx.x * 28 + i] = 0ull;
}

extern "C" void kernel_launch(void* const* d_in, const int* in_sizes, int n_in,
                              void* d_out, int out_size, void* d_ws, size_t ws_size,
                              hipStream_t stream) {
  Params p;
  p.x       = (const float*)d_in[0];
  p.state   = (const float*)d_in[1];
  p.ln1w    = (const float*)d_in[2];
  p.ln1b    = (const float*)d_in[3];
  p.ln2w    = (const float*)d_in[4];
  p.ln2b    = (const float*)d_in[5];
  p.td      = (const float*)d_in[6];
  p.tf      = (const float*)d_in[7];
  p.kktk    = (const float*)d_in[8];
  p.vvtv    = (const float*)d_in[9];
  p.rrtr    = (const float*)d_in[10];
  p.key     = (const float*)d_in[11];
  p.outputv = (const float*)d_in[12];
  p.tmk     = (const float*)d_in[13];
  p.tmr     = (const float*)d_in[14];
  p.kffn    = (const float*)d_in[15];
  p.rffn    = (const float*)d_in[16];
  p.vffn    = (const float*)d_in[17];
  p.out     = (float*)d_out;
  p.q       = (u64*)d_ws;            // 7168 u64 = 57344 B

  rwkv_init<<<1, NB, 0, stream>>>(p.q);
  rwkv_persistent<<<NB, NT, 0, stream>>>(p);
}